// Round 8
// baseline (196.253 us; speedup 1.0000x reference)
//
#include <hip/hip_runtime.h>
#include <hip/hip_bf16.h>

typedef __attribute__((ext_vector_type(8))) short bf16x8;
typedef __attribute__((ext_vector_type(4))) float f32x4;
typedef unsigned int u32;
typedef unsigned short u16;

#define NPOS 147456
#define NTILES 9216
#define NBLK 1024          // 4 blocks/CU (34 KB LDS, VGPR<=128)
#define ITERS 9            // NTILES / NBLK (exact)

__device__ inline u16 bfc(float f) {
  union { __hip_bfloat16 h; u16 s; } u;
  u.h = __float2bfloat16(f);
  return u.s;
}

// ---------------------------------------------------------------------------
// Prologue: bake bf16 weight fragments into ws (unchanged from R3-R7).
// frag = 512 u16; frag elem (lane,e): A[row=lane&15][k=(lane>>4)*8+e].
// ---------------------------------------------------------------------------
__global__ void prep_kernel(const float* __restrict__ wq, const float* __restrict__ wk,
                            const float* __restrict__ wv, const float* __restrict__ wo,
                            u16* __restrict__ wsf) {
  int gid = blockIdx.x * 256 + threadIdx.x;   // [0, 24576)
  int idx, which;
  if (gid < 8192)       { idx = gid;         which = 0; }
  else if (gid < 12288) { idx = gid - 8192;  which = 1; }
  else if (gid < 16384) { idx = gid - 12288; which = 2; }
  else                  { idx = gid - 16384; which = 3; }
  int fragid = idx >> 9, lane = (idx >> 3) & 63, e = idx & 7;
  int l15 = lane & 15, g = lane >> 4;
  float v;
  if (which == 0) {        // wq: [4][128][16]
    int n = fragid >> 2, kc = fragid & 3;
    int c = kc * 32 + g * 8 + e;
    v = wq[n * 2048 + c * 16 + l15] * 0.25f;   // fold D^-0.5
  } else if (which == 1) { // wk: [4][64][16]
    int n = fragid >> 1, kc = fragid & 1;
    int c = kc * 32 + g * 8 + e;
    v = wk[n * 1024 + c * 16 + l15];
  } else if (which == 2) { // wv
    int n = fragid >> 1, kc = fragid & 1;
    int c = kc * 32 + g * 8 + e;
    v = wv[n * 1024 + c * 16 + l15];
  } else {                 // wo: [4][16][128]
    int n8 = fragid >> 1, kc = fragid & 1;
    int hd = kc * 32 + g * 8 + e;
    v = wo[(hd >> 4) * 2048 + (hd & 15) * 128 + n8 * 16 + l15];
  }
  wsf[gid] = bfc(v);
}

#define WQF(n, kc)  ((((n) * 4 + (kc))) * 64)
#define WKF(n, kc)  ((16 + (n) * 2 + (kc)) * 64)
#define WVF(n, kc)  ((24 + (n) * 2 + (kc)) * 64)
#define WOF(n8, kc) ((32 + (n8) * 2 + (kc)) * 64)

typedef const __attribute__((address_space(1))) u32 gas_u32;
typedef __attribute__((address_space(3))) u32 las_u32;

#define STR2_(x) #x
#define WAITVM(n) asm volatile("s_waitcnt vmcnt(" STR2_(n) ")" ::: "memory")

// ---------------------------------------------------------------------------
// Main: 1024 blocks x 4 waves (wave h = head h), 9 tiles/block.
// tpr: 2x16KB LDS double-buffer via global_load_lds, staged 2 tiles ahead.
// q:   2 register landing buffers (qvA/qvB), loaded 2 tiles ahead; body it
//      consumes qv[it&1] then reuses that buffer as landing for tile it+2.
// vmcnt ladder: WAITVM(4) body0, WAITVM(14) steady
//   (queue at body it: [qload(it)8, STAGE(it)4, st2][qload(it+1)8,
//    STAGE(it+1)4, st2] = 28 -> drain to 14 completes tile it's q + tpr).
// ---------------------------------------------------------------------------
__global__ __launch_bounds__(256, 4) void tpa_kernel(
    const float* __restrict__ qe, const float* __restrict__ tpr,
    const float* __restrict__ tmk_p, const float* __restrict__ ob,
    const u16* __restrict__ wsf, float* __restrict__ out)
{
  __shared__ int4 inbuf4[2][1024];   // 2 x 16 KB tpr tile, XOR-swizzled rows
  __shared__ u32 wvsh32[512];        // 2 KB WV exchange [pos][hd] bf16, swizzled
  char* const inb0 = (char*)inbuf4[0];
  char* const inb1 = (char*)inbuf4[1];
  char* const wvsh = (char*)wvsh32;

  const int tid = threadIdx.x;
  const int wid = tid >> 6;           // wave id = head h
  const int lane = tid & 63;
  const int l15 = lane & 15, g = lane >> 4;
  const int swz = (l15 & 7) << 4;
  const int h = wid;

  // ---- per-lane DMA source bases (inverse-swizzled global addresses) ----
  // chunk m = (wid*4+j)*64 + lane in [0,1024): t=m>>8, pos=(m>>4)&15, c16=m&15
  const char* dmab[4];
  #pragma unroll
  for (int j = 0; j < 4; ++j) {
    int m = (wid * 4 + j) * 64 + lane;
    int t = m >> 8, pos = (m >> 4) & 15, c16 = m & 15;
    int inner = (c16 * 16) ^ ((pos & 7) << 4);
    dmab[j] = (const char*)tpr + ((size_t)t * NPOS + pos) * 256 + inner;
  }

#define STAGE(DST, P)                                                          \
  { _Pragma("unroll") for (int j = 0; j < 4; ++j) {                            \
      const char* s_ = dmab[j] + (size_t)(P) * 256;                            \
      char* d_ = (DST) + (wid * 4 + j) * 1024;                                 \
      __builtin_amdgcn_global_load_lds((gas_u32*)s_, (las_u32*)d_, 16, 0, 0); } }

#define LOADQ(QV, P)                                                           \
  { const f32x4* qb = reinterpret_cast<const f32x4*>(qe) + ((P) + l15) * 32 + g * 2; \
    _Pragma("unroll")                                                          \
    for (int kc = 0; kc < 4; ++kc) {                                           \
      QV[kc * 2 + 0] = qb[kc * 8 + 0];                                         \
      QV[kc * 2 + 1] = qb[kc * 8 + 1];                                         \
    } }

  // ---- prologue: weights/consts; q(t0),q(t1) to regs; stage tiles 0,1 ----
  const bf16x8* wf = (const bf16x8*)wsf;
  bf16x8 wqf[4], wkf[2], wvf[2], wof[2][2];
  #pragma unroll
  for (int kc = 0; kc < 4; ++kc) wqf[kc] = wf[WQF(h, kc) + lane];
  #pragma unroll
  for (int kc = 0; kc < 2; ++kc) {
    wkf[kc] = wf[WKF(h, kc) + lane];
    wvf[kc] = wf[WVF(h, kc) + lane];
    wof[0][kc] = wf[WOF(2 * h + 0, kc) + lane];
    wof[1][kc] = wf[WOF(2 * h + 1, kc) + lane];
  }

  const float m0 = tmk_p[0], m1 = tmk_p[1], m2 = tmk_p[2], m3 = tmk_p[3];
  const float biasv[4] = {65504.0f * (m0 - 1.0f), 65504.0f * (m1 - 1.0f),
                          65504.0f * (m2 - 1.0f), 65504.0f * (m3 - 1.0f)};
  const float tmk = (m0 + m1 + m2 + m3 > 0.0f) ? 1.0f : 0.0f;

  f32x4 obf[2];
  {
    const f32x4* obase = reinterpret_cast<const f32x4*>(ob);
    #pragma unroll
    for (int j = 0; j < 2; ++j) {
      const f32x4 o = obase[(2 * h + j) * 4 + g];
      #pragma unroll
      for (int r = 0; r < 4; ++r) obf[j][r] = o[r] * tmk;
    }
  }

  f32x4 qvA[8], qvB[8];
  LOADQ(qvA, blockIdx.x * 16)
  LOADQ(qvB, (blockIdx.x + NBLK) * 16)
  __builtin_amdgcn_sched_barrier(0);
  STAGE(inb0, blockIdx.x * 16)
  STAGE(inb1, (blockIdx.x + NBLK) * 16)
  __builtin_amdgcn_sched_barrier(0);

#define BODY(IT, CB, QV, WN)                                                   \
{                                                                              \
  const int it_ = (IT);                                                        \
  const int p0 = (blockIdx.x + it_ * NBLK) * 16;                               \
  __builtin_amdgcn_sched_barrier(0);                                           \
  WAITVM(WN);                                                                  \
  __builtin_amdgcn_s_barrier();                                                \
  __builtin_amdgcn_sched_barrier(0);                                           \
  f32x4 qT = (f32x4){0.f, 0.f, 0.f, 0.f};                                      \
  _Pragma("unroll")                                                            \
  for (int kc = 0; kc < 4; ++kc) {                                             \
    bf16x8 aq;                                                                 \
    _Pragma("unroll")                                                          \
    for (int e = 0; e < 4; ++e) {                                              \
      aq[e]     = (short)bfc(QV[kc * 2 + 0][e]);                               \
      aq[e + 4] = (short)bfc(QV[kc * 2 + 1][e]);                               \
    }                                                                          \
    qT = __builtin_amdgcn_mfma_f32_16x16x32_bf16(wqf[kc], aq, qT, 0, 0, 0);    \
  }                                                                            \
  float ssum = 0.f;                                                            \
  f32x4 wvT = (f32x4){0.f, 0.f, 0.f, 0.f};                                     \
  _Pragma("unroll")                                                            \
  for (int t = 0; t < 4; ++t) {                                                \
    const char* trow = (CB) + t * 4096 + l15 * 256;                            \
    bf16x8 at0, at1;                                                           \
    { f32x4 lo = *(const f32x4*)(trow + ((g * 32) ^ swz));                     \
      f32x4 hi = *(const f32x4*)(trow + ((g * 32 + 16) ^ swz));                \
      _Pragma("unroll")                                                        \
      for (int e = 0; e < 4; ++e) { at0[e] = (short)bfc(lo[e]); at0[e + 4] = (short)bfc(hi[e]); } } \
    { f32x4 lo = *(const f32x4*)(trow + ((128 + g * 32) ^ swz));               \
      f32x4 hi = *(const f32x4*)(trow + ((128 + g * 32 + 16) ^ swz));          \
      _Pragma("unroll")                                                        \
      for (int e = 0; e < 4; ++e) { at1[e] = (short)bfc(lo[e]); at1[e + 4] = (short)bfc(hi[e]); } } \
    f32x4 kT = (f32x4){0.f, 0.f, 0.f, 0.f};                                    \
    f32x4 vT = (f32x4){0.f, 0.f, 0.f, 0.f};                                    \
    kT = __builtin_amdgcn_mfma_f32_16x16x32_bf16(wkf[0], at0, kT, 0, 0, 0);    \
    kT = __builtin_amdgcn_mfma_f32_16x16x32_bf16(wkf[1], at1, kT, 0, 0, 0);    \
    vT = __builtin_amdgcn_mfma_f32_16x16x32_bf16(wvf[0], at0, vT, 0, 0, 0);    \
    vT = __builtin_amdgcn_mfma_f32_16x16x32_bf16(wvf[1], at1, vT, 0, 0, 0);    \
    float lg = qT[0] * kT[0] + qT[1] * kT[1] + qT[2] * kT[2] + qT[3] * kT[3];  \
    lg += __shfl_xor(lg, 16);                                                  \
    lg += __shfl_xor(lg, 32);                                                  \
    const float w = __expf(lg + biasv[t]);                                     \
    ssum += w;                                                                 \
    _Pragma("unroll")                                                          \
    for (int r = 0; r < 4; ++r) wvT[r] += w * vT[r];                           \
  }                                                                            \
  { const float inv = tmk / fmaxf(ssum, 1e-30f);                               \
    u32 pk0 = (u32)bfc(wvT[0] * inv) | ((u32)bfc(wvT[1] * inv) << 16);         \
    u32 pk1 = (u32)bfc(wvT[2] * inv) | ((u32)bfc(wvT[3] * inv) << 16);         \
    const int hb = h * 32 + g * 8;                                             \
    *(u32*)(wvsh + ((l15 * 128 + hb) ^ swz))     = pk0;                        \
    *(u32*)(wvsh + ((l15 * 128 + hb + 4) ^ swz)) = pk1; }                      \
  __builtin_amdgcn_sched_barrier(0);                                           \
  asm volatile("s_waitcnt lgkmcnt(0)" ::: "memory");                           \
  __builtin_amdgcn_s_barrier();   /* CB fully read by all waves */             \
  __builtin_amdgcn_sched_barrier(0);                                           \
  { const int nq = (it_ + 2 < ITERS) ? it_ + 2 : it_;                          \
    LOADQ(QV, (blockIdx.x + nq * NBLK) * 16) }   /* 2-ahead into same buf */   \
  __builtin_amdgcn_sched_barrier(0);                                           \
  { const int sit = (it_ + 2 < ITERS) ? it_ + 2 : it_;                         \
    STAGE(CB, (blockIdx.x + sit * NBLK) * 16) }                                \
  __builtin_amdgcn_sched_barrier(0);                                           \
  bf16x8 bwv0 = *(const bf16x8*)(wvsh + ((l15 * 128 + g * 16)      ^ swz));    \
  bf16x8 bwv1 = *(const bf16x8*)(wvsh + ((l15 * 128 + 64 + g * 16) ^ swz));    \
  _Pragma("unroll")                                                            \
  for (int j = 0; j < 2; ++j) {                                                \
    f32x4 acc = (f32x4){0.f, 0.f, 0.f, 0.f};                                   \
    acc = __builtin_amdgcn_mfma_f32_16x16x32_bf16(wof[j][0], bwv0, acc, 0, 0, 0); \
    acc = __builtin_amdgcn_mfma_f32_16x16x32_bf16(wof[j][1], bwv1, acc, 0, 0, 0); \
    f32x4 res;                                                                 \
    _Pragma("unroll")                                                          \
    for (int r = 0; r < 4; ++r) res[r] = acc[r] + obf[j][r];                   \
    *(f32x4*)(out + (size_t)(p0 + l15) * 128 + (2 * h + j) * 16 + g * 4) = res; \
  }                                                                            \
}

  BODY(0, inb0, qvA, 4)
  for (int ith = 0; ith < 4; ++ith) {
    BODY(2 * ith + 1, inb1, qvB, 14)
    BODY(2 * ith + 2, inb0, qvA, 14)
  }
}

extern "C" void kernel_launch(void* const* d_in, const int* in_sizes, int n_in,
                              void* d_out, int out_size, void* d_ws, size_t ws_size,
                              hipStream_t stream) {
  const float* qe  = (const float*)d_in[0];
  const float* tpr = (const float*)d_in[1];
  const float* tmk = (const float*)d_in[2];
  const float* wq  = (const float*)d_in[3];
  const float* wk  = (const float*)d_in[4];
  const float* wv  = (const float*)d_in[5];
  const float* wo  = (const float*)d_in[6];
  const float* ob  = (const float*)d_in[7];
  float* out = (float*)d_out;
  u16* wsf = (u16*)d_ws;

  prep_kernel<<<96, 256, 0, stream>>>(wq, wk, wv, wo, wsf);
  tpa_kernel<<<NBLK, 256, 0, stream>>>(qe, tpr, tmk, ob, wsf, out);
}

// Round 9
// 61.529 us; speedup vs baseline: 3.1896x; 3.1896x over previous
//
#include <hip/hip_runtime.h>
#include <hip/hip_bf16.h>

typedef __attribute__((ext_vector_type(8))) short bf16x8;
typedef __attribute__((ext_vector_type(4))) float f32x4;
typedef unsigned int u32;
typedef unsigned short u16;

#define NPOS 147456
#define NTILES 9216
#define NBLK 1536          // 6 blocks/CU (26 KB LDS), 6 iters/block
#define ITERS 6            // NTILES / NBLK (exact)

__device__ inline u16 bfc(float f) {
  union { __hip_bfloat16 h; u16 s; } u;
  u.h = __float2bfloat16(f);
  return u.s;
}

// ---------------------------------------------------------------------------
// Prologue: bake bf16 weight fragments into ws (unchanged from R3-R8).
// frag = 512 u16; frag elem (lane,e): A[row=lane&15][k=(lane>>4)*8+e].
// ---------------------------------------------------------------------------
__global__ void prep_kernel(const float* __restrict__ wq, const float* __restrict__ wk,
                            const float* __restrict__ wv, const float* __restrict__ wo,
                            u16* __restrict__ wsf) {
  int gid = blockIdx.x * 256 + threadIdx.x;   // [0, 24576)
  int idx, which;
  if (gid < 8192)       { idx = gid;         which = 0; }
  else if (gid < 12288) { idx = gid - 8192;  which = 1; }
  else if (gid < 16384) { idx = gid - 12288; which = 2; }
  else                  { idx = gid - 16384; which = 3; }
  int fragid = idx >> 9, lane = (idx >> 3) & 63, e = idx & 7;
  int l15 = lane & 15, g = lane >> 4;
  float v;
  if (which == 0) {        // wq: [4][128][16]
    int n = fragid >> 2, kc = fragid & 3;
    int c = kc * 32 + g * 8 + e;
    v = wq[n * 2048 + c * 16 + l15] * 0.25f;   // fold D^-0.5
  } else if (which == 1) { // wk: [4][64][16]
    int n = fragid >> 1, kc = fragid & 1;
    int c = kc * 32 + g * 8 + e;
    v = wk[n * 1024 + c * 16 + l15];
  } else if (which == 2) { // wv
    int n = fragid >> 1, kc = fragid & 1;
    int c = kc * 32 + g * 8 + e;
    v = wv[n * 1024 + c * 16 + l15];
  } else {                 // wo: [4][16][128]
    int n8 = fragid >> 1, kc = fragid & 1;
    int hd = kc * 32 + g * 8 + e;
    v = wo[(hd >> 4) * 2048 + (hd & 15) * 128 + n8 * 16 + l15];
  }
  wsf[gid] = bfc(v);
}

#define WQF(n, kc)  ((((n) * 4 + (kc))) * 64)
#define WKF(n, kc)  ((16 + (n) * 2 + (kc)) * 64)
#define WVF(n, kc)  ((24 + (n) * 2 + (kc)) * 64)
#define WOF(n8, kc) ((32 + (n8) * 2 + (kc)) * 64)

typedef const __attribute__((address_space(1))) u32 gas_u32;
typedef __attribute__((address_space(3))) u32 las_u32;

#define STR2_(x) #x
#define WAITVM(n) asm volatile("s_waitcnt vmcnt(" STR2_(n) ")" ::: "memory")
#define SBAR      __builtin_amdgcn_s_barrier()
#define SCHB      __builtin_amdgcn_sched_barrier(0)
#define WAITLGKM  asm volatile("s_waitcnt lgkmcnt(0)" ::: "memory")

// ---------------------------------------------------------------------------
// Main: 1536 blocks x 4 waves (wave h = head h), 6 tiles/block, everything
// DMA'd via global_load_lds (zero landing VGPRs). LDS 26 KB:
//   qls  8 KB  [pos][c]     (single buffer, restaged after consume barrier)
//   thA  8 KB  t=0,1 halves (restaged after consume barrier)
//   thB  8 KB  t=2,3 halves (restaged after exchange barrier)
//   wvsh 2 KB  WV exchange
// vmcnt ladder: body0 (2,4), steady (4,4). 2 stores/thread/body.
// ---------------------------------------------------------------------------
__global__ __launch_bounds__(256) void tpa_kernel(
    const float* __restrict__ qe, const float* __restrict__ tpr,
    const float* __restrict__ tmk_p, const float* __restrict__ ob,
    const u16* __restrict__ wsf, float* __restrict__ out)
{
  __shared__ int4 qls4[512];     // 8 KB
  __shared__ int4 thA4[512];     // 8 KB
  __shared__ int4 thB4[512];     // 8 KB
  __shared__ u32 wvsh32[512];    // 2 KB
  char* const qls  = (char*)qls4;
  char* const thA  = (char*)thA4;
  char* const thB  = (char*)thB4;
  char* const wvsh = (char*)wvsh32;

  const int tid = threadIdx.x;
  const int wid = tid >> 6;           // wave id = head h
  const int lane = tid & 63;
  const int l15 = lane & 15, g = lane >> 4;
  const int swz = (l15 & 7) << 4;
  const int h = wid;

  // ---- per-lane DMA source bases (inverse-swizzled global addresses) ----
  // q: 512 chunks of 16B; m=(wid*2+j)*64+lane: pos=m>>5, c=m&31
  const char* qdb[2];
  #pragma unroll
  for (int j = 0; j < 2; ++j) {
    int m = (wid * 2 + j) * 64 + lane;
    int pos = m >> 5, c16 = m & 31;
    qdb[j] = (const char*)qe + (size_t)pos * 512 + ((c16 * 16) ^ ((pos & 7) << 4));
  }
  // tpr halves: 512 chunks; m=(wid*2+j)*64+lane: t=TB+(m>>8), pos=(m>>4)&15, c=m&15
  const char* tdb[2][2];   // [half][j]
  #pragma unroll
  for (int hf = 0; hf < 2; ++hf)
    #pragma unroll
    for (int j = 0; j < 2; ++j) {
      int m = (wid * 2 + j) * 64 + lane;
      int t = hf * 2 + (m >> 8), pos = (m >> 4) & 15, c16 = m & 15;
      tdb[hf][j] = (const char*)tpr + ((size_t)t * NPOS + pos) * 256 +
                   ((c16 * 16) ^ ((pos & 7) << 4));
    }

#define STAGE_Q(P)                                                             \
  { _Pragma("unroll") for (int j = 0; j < 2; ++j) {                            \
      const char* s_ = qdb[j] + (size_t)(P) * 512;                             \
      char* d_ = qls + (wid * 2 + j) * 1024;                                   \
      __builtin_amdgcn_global_load_lds((gas_u32*)s_, (las_u32*)d_, 16, 0, 0); } }

#define STAGE_T(HF, DST, P)                                                    \
  { _Pragma("unroll") for (int j = 0; j < 2; ++j) {                            \
      const char* s_ = tdb[HF][j] + (size_t)(P) * 256;                         \
      char* d_ = (DST) + (wid * 2 + j) * 1024;                                 \
      __builtin_amdgcn_global_load_lds((gas_u32*)s_, (las_u32*)d_, 16, 0, 0); } }

  // ---- prologue: weights/consts; stage tile0 (q, tA, tB) ----
  const bf16x8* wf = (const bf16x8*)wsf;
  bf16x8 wqf[4], wkf[2], wvf[2], wof[2][2];
  #pragma unroll
  for (int kc = 0; kc < 4; ++kc) wqf[kc] = wf[WQF(h, kc) + lane];
  #pragma unroll
  for (int kc = 0; kc < 2; ++kc) {
    wkf[kc] = wf[WKF(h, kc) + lane];
    wvf[kc] = wf[WVF(h, kc) + lane];
    wof[0][kc] = wf[WOF(2 * h + 0, kc) + lane];
    wof[1][kc] = wf[WOF(2 * h + 1, kc) + lane];
  }

  const float m0 = tmk_p[0], m1 = tmk_p[1], m2 = tmk_p[2], m3 = tmk_p[3];
  const float biasv[4] = {65504.0f * (m0 - 1.0f), 65504.0f * (m1 - 1.0f),
                          65504.0f * (m2 - 1.0f), 65504.0f * (m3 - 1.0f)};
  const float tmk = (m0 + m1 + m2 + m3 > 0.0f) ? 1.0f : 0.0f;

  f32x4 obf[2];
  {
    const f32x4* obase = reinterpret_cast<const f32x4*>(ob);
    #pragma unroll
    for (int j = 0; j < 2; ++j) {
      const f32x4 o = obase[(2 * h + j) * 4 + g];
      #pragma unroll
      for (int r = 0; r < 4; ++r) obf[j][r] = o[r] * tmk;
    }
  }

  SCHB;
  STAGE_Q(blockIdx.x * 16)
  STAGE_T(0, thA, blockIdx.x * 16)
  STAGE_T(1, thB, blockIdx.x * 16)
  SCHB;

#define TSTEP(TROW, BIAS)                                                      \
  { bf16x8 at0, at1;                                                           \
    { f32x4 lo = *(const f32x4*)((TROW) + ((g * 32) ^ swz));                   \
      f32x4 hi = *(const f32x4*)((TROW) + ((g * 32 + 16) ^ swz));              \
      _Pragma("unroll")                                                        \
      for (int e = 0; e < 4; ++e) { at0[e] = (short)bfc(lo[e]); at0[e + 4] = (short)bfc(hi[e]); } } \
    { f32x4 lo = *(const f32x4*)((TROW) + ((128 + g * 32) ^ swz));             \
      f32x4 hi = *(const f32x4*)((TROW) + ((128 + g * 32 + 16) ^ swz));        \
      _Pragma("unroll")                                                        \
      for (int e = 0; e < 4; ++e) { at1[e] = (short)bfc(lo[e]); at1[e + 4] = (short)bfc(hi[e]); } } \
    f32x4 kT = (f32x4){0.f, 0.f, 0.f, 0.f};                                    \
    f32x4 vT = (f32x4){0.f, 0.f, 0.f, 0.f};                                    \
    kT = __builtin_amdgcn_mfma_f32_16x16x32_bf16(wkf[0], at0, kT, 0, 0, 0);    \
    kT = __builtin_amdgcn_mfma_f32_16x16x32_bf16(wkf[1], at1, kT, 0, 0, 0);    \
    vT = __builtin_amdgcn_mfma_f32_16x16x32_bf16(wvf[0], at0, vT, 0, 0, 0);    \
    vT = __builtin_amdgcn_mfma_f32_16x16x32_bf16(wvf[1], at1, vT, 0, 0, 0);    \
    float lg = qT[0] * kT[0] + qT[1] * kT[1] + qT[2] * kT[2] + qT[3] * kT[3];  \
    lg += __shfl_xor(lg, 16);                                                  \
    lg += __shfl_xor(lg, 32);                                                  \
    const float w = __expf(lg + (BIAS));                                       \
    ssum += w;                                                                 \
    _Pragma("unroll")                                                          \
    for (int r = 0; r < 4; ++r) wvT[r] += w * vT[r]; }

#define BODY(IT, WNA)                                                          \
{                                                                              \
  const int it_ = (IT);                                                        \
  const int p0 = (blockIdx.x + it_ * NBLK) * 16;                               \
  const int np0 = (blockIdx.x + ((it_ + 1 < ITERS) ? it_ + 1 : it_) * NBLK) * 16; \
  /* phase 1: q + tA ready */                                                  \
  SCHB; WAITVM(WNA); SBAR; SCHB;                                               \
  f32x4 qT = (f32x4){0.f, 0.f, 0.f, 0.f};                                      \
  { const char* qrow = qls + l15 * 512;                                        \
    _Pragma("unroll")                                                          \
    for (int kc = 0; kc < 4; ++kc) {                                           \
      const int cb = kc * 128 + g * 32;                                        \
      f32x4 lo = *(const f32x4*)(qrow + ((cb) ^ swz));                         \
      f32x4 hi = *(const f32x4*)(qrow + ((cb + 16) ^ swz));                    \
      bf16x8 aq;                                                               \
      _Pragma("unroll")                                                        \
      for (int e = 0; e < 4; ++e) { aq[e] = (short)bfc(lo[e]); aq[e + 4] = (short)bfc(hi[e]); } \
      qT = __builtin_amdgcn_mfma_f32_16x16x32_bf16(wqf[kc], aq, qT, 0, 0, 0);  \
    } }                                                                        \
  float ssum = 0.f;                                                            \
  f32x4 wvT = (f32x4){0.f, 0.f, 0.f, 0.f};                                     \
  TSTEP(thA + 0 * 4096 + l15 * 256, biasv[0])                                  \
  TSTEP(thA + 1 * 4096 + l15 * 256, biasv[1])                                  \
  /* q + tA consumed -> restage for next tile */                               \
  SCHB; WAITLGKM; SBAR; SCHB;                                                  \
  STAGE_Q(np0)                                                                 \
  STAGE_T(0, thA, np0)                                                         \
  /* phase 2: tB ready */                                                      \
  SCHB; WAITVM(4); SBAR; SCHB;                                                 \
  TSTEP(thB + 0 * 4096 + l15 * 256, biasv[2])                                  \
  TSTEP(thB + 1 * 4096 + l15 * 256, biasv[3])                                  \
  { const float inv = tmk / fmaxf(ssum, 1e-30f);                               \
    u32 pk0 = (u32)bfc(wvT[0] * inv) | ((u32)bfc(wvT[1] * inv) << 16);         \
    u32 pk1 = (u32)bfc(wvT[2] * inv) | ((u32)bfc(wvT[3] * inv) << 16);         \
    const int hb = h * 32 + g * 8;                                             \
    *(u32*)(wvsh + ((l15 * 128 + hb) ^ swz))     = pk0;                        \
    *(u32*)(wvsh + ((l15 * 128 + hb + 4) ^ swz)) = pk1; }                      \
  /* exchange ready + tB consumed */                                           \
  SCHB; WAITLGKM; SBAR; SCHB;                                                  \
  { bf16x8 bwv0 = *(const bf16x8*)(wvsh + ((l15 * 128 + g * 16)      ^ swz));  \
    bf16x8 bwv1 = *(const bf16x8*)(wvsh + ((l15 * 128 + 64 + g * 16) ^ swz));  \
    _Pragma("unroll")                                                          \
    for (int j = 0; j < 2; ++j) {                                              \
      f32x4 acc = (f32x4){0.f, 0.f, 0.f, 0.f};                                 \
      acc = __builtin_amdgcn_mfma_f32_16x16x32_bf16(wof[j][0], bwv0, acc, 0, 0, 0); \
      acc = __builtin_amdgcn_mfma_f32_16x16x32_bf16(wof[j][1], bwv1, acc, 0, 0, 0); \
      f32x4 res;                                                               \
      _Pragma("unroll")                                                        \
      for (int r = 0; r < 4; ++r) res[r] = acc[r] + obf[j][r];                 \
      *(f32x4*)(out + (size_t)(p0 + l15) * 128 + (2 * h + j) * 16 + g * 4) = res; \
    } }                                                                        \
  SCHB;                                                                        \
  STAGE_T(1, thB, np0)                                                         \
  SCHB;                                                                        \
}

  BODY(0, 2)
  #pragma unroll 1
  for (int it = 1; it < ITERS; ++it) {
    BODY(it, 4)
  }
}

extern "C" void kernel_launch(void* const* d_in, const int* in_sizes, int n_in,
                              void* d_out, int out_size, void* d_ws, size_t ws_size,
                              hipStream_t stream) {
  const float* qe  = (const float*)d_in[0];
  const float* tpr = (const float*)d_in[1];
  const float* tmk = (const float*)d_in[2];
  const float* wq  = (const float*)d_in[3];
  const float* wk  = (const float*)d_in[4];
  const float* wv  = (const float*)d_in[5];
  const float* wo  = (const float*)d_in[6];
  const float* ob  = (const float*)d_in[7];
  float* out = (float*)d_out;
  u16* wsf = (u16*)d_ws;

  prep_kernel<<<96, 256, 0, stream>>>(wq, wk, wv, wo, wsf);
  tpa_kernel<<<NBLK, 256, 0, stream>>>(qe, tpr, tmk, ob, wsf, out);
}